// Round 1
// 643.535 us; speedup vs baseline: 1.0029x; 1.0029x over previous
//
#include <hip/hip_runtime.h>

typedef __bf16 bf16x8 __attribute__((ext_vector_type(8)));
typedef float floatx4 __attribute__((ext_vector_type(4)));

__device__ __forceinline__ unsigned short f2bf(float f) {
    unsigned int u = __builtin_bit_cast(unsigned int, f);
    u += 0x7fffu + ((u >> 16) & 1u);   // round-to-nearest-even
    return (unsigned short)(u >> 16);
}

// ---------------- kernel 0: conv_weight -> bf16, row sums S[o] ----------------
__global__ __launch_bounds__(256) void prep_kernel(const float* __restrict__ cw,
                                                   unsigned short* __restrict__ cwb,
                                                   float* __restrict__ S) {
    int o = blockIdx.x;
    int c = threadIdx.x;
    float w = cw[o * 256 + c];
    cwb[o * 256 + c] = f2bf(w);
    float s = w;
    #pragma unroll
    for (int off = 32; off; off >>= 1) s += __shfl_xor(s, off);
    __shared__ float ps[4];
    if ((c & 63) == 0) ps[c >> 6] = s;
    __syncthreads();
    if (c == 0) S[o] = ps[0] + ps[1] + ps[2] + ps[3];
}

// ---------------- fused: z=x+y, LN over w, 1x1 conv over c (MFMA), ReLU ----------------
// block = one (b,h) plane: M=256 o, N=256 w, K=256 c. 1024 threads = 16 waves
// (was 8): LDS is pinned at 128 KiB (full plane, LN needs whole rows + GEMM
// needs whole columns) -> 1 block/CU regardless, so raise waves/CU 8->16 to
// hide HBM latency + shuffle chains. VGPR must stay <=128 for 4 waves/SIMD.
// LDS tile zt[w][c] bf16, chunk-XOR swizzled: 16B chunk index
// chunk' = chunk ^ (w&7) on a 512B row stride -> both ds_write_b128 (LN
// transpose) and ds_read_b128 (B-frags) sit at the 8-lane/4-bank-cluster floor.
__global__ __launch_bounds__(1024) void fused_kernel(const float* __restrict__ x,
                                                     const float* __restrict__ y,
                                                     const float* __restrict__ lnw,
                                                     const float* __restrict__ lnb,
                                                     const unsigned short* __restrict__ cwb,
                                                     const float* __restrict__ S,
                                                     float* __restrict__ out) {
    __shared__ unsigned short zt[256 * 256];   // [w][swizzled c], 131072 B

    int b = blockIdx.x >> 8;
    int h = blockIdx.x & 255;
    int t = threadIdx.x;
    int wave = t >> 6;
    int lane = t & 63;
    size_t plane = ((size_t)b << 24) + ((size_t)h << 8);   // + c*65536 + w

    // ---- phase 1: LN. wave handles c = wave*16 .. +15, in 2 groups of 8 rows ----
    float lw[4];
    #pragma unroll
    for (int j = 0; j < 4; ++j) lw[j] = lnw[lane + 64 * j];

    #pragma unroll
    for (int g = 0; g < 2; ++g) {
        int c0 = wave * 16 + g * 8;
        unsigned short fr[4][8];   // [j: w-group][r: c within group]
        #pragma unroll
        for (int r = 0; r < 8; ++r) {
            int c = c0 + r;
            const float* xp = x + plane + ((size_t)c << 16);
            const float* yp = y + plane + ((size_t)c << 16);
            float z[4];
            float s = 0.0f, q = 0.0f;
            #pragma unroll
            for (int j = 0; j < 4; ++j) {
                float xv = xp[lane + 64 * j];
                float yv = yp[lane + 64 * j];
                z[j] = xv + yv;
                s += z[j];
                q += z[j] * z[j];
            }
            #pragma unroll
            for (int off = 32; off; off >>= 1) {
                s += __shfl_xor(s, off);
                q += __shfl_xor(q, off);
            }
            float mean = s * (1.0f / 256.0f);
            float rstd = rsqrtf(q * (1.0f / 256.0f) - mean * mean + 1e-5f);
            #pragma unroll
            for (int j = 0; j < 4; ++j) fr[j][r] = f2bf((z[j] - mean) * rstd * lw[j]);
        }
        int chunk = wave * 2 + g;          // c0 >> 3, 0..31
        int chunkp = chunk ^ (lane & 7);   // w&7 == lane&7
        #pragma unroll
        for (int j = 0; j < 4; ++j) {
            int w = lane + 64 * j;
            uint4 v;
            v.x = (unsigned int)fr[j][0] | ((unsigned int)fr[j][1] << 16);
            v.y = (unsigned int)fr[j][2] | ((unsigned int)fr[j][3] << 16);
            v.z = (unsigned int)fr[j][4] | ((unsigned int)fr[j][5] << 16);
            v.w = (unsigned int)fr[j][6] | ((unsigned int)fr[j][7] << 16);
            *(uint4*)&zt[w * 256 + chunkp * 8] = v;
        }
    }
    __syncthreads();

    // ---- phase 2: GEMM. wave -> o_base = (wave&3)*64, pixel tile p0 = (wave>>2)*64 ----
    int llo = lane & 15;
    int lhi = lane >> 4;
    int o_base = (wave & 3) * 64;
    int p0 = (wave >> 2) * 64;
    float* ob = out + plane;   // + o*65536 + w

    floatx4 acc[4][4];
    #pragma unroll
    for (int u = 0; u < 4; ++u)
        #pragma unroll
        for (int s2 = 0; s2 < 4; ++s2)
            #pragma unroll
            for (int r = 0; r < 4; ++r) acc[u][s2][r] = 0.0f;

    #pragma unroll
    for (int kt = 0; kt < 8; ++kt) {
        bf16x8 bfrag[4], afrag[4];
        #pragma unroll
        for (int s2 = 0; s2 < 4; ++s2) {
            int w = p0 + 16 * s2 + llo;
            int chunkp = (kt * 4 + lhi) ^ (llo & 7);   // w&7 == llo&7
            bfrag[s2] = *(const bf16x8*)&zt[w * 256 + chunkp * 8];
        }
        #pragma unroll
        for (int u = 0; u < 4; ++u)
            afrag[u] = *(const bf16x8*)(cwb + (size_t)(o_base + 16 * u + llo) * 256 + kt * 32 + lhi * 8);
        #pragma unroll
        for (int u = 0; u < 4; ++u)
            #pragma unroll
            for (int s2 = 0; s2 < 4; ++s2)
                acc[u][s2] = __builtin_amdgcn_mfma_f32_16x16x32_bf16(afrag[u], bfrag[s2], acc[u][s2], 0, 0, 0);
    }

    // ---- epilogue: + S[o]*lnb[w], ReLU, store ----
    float lnbv[4];
    #pragma unroll
    for (int s2 = 0; s2 < 4; ++s2) lnbv[s2] = lnb[p0 + 16 * s2 + llo];
    #pragma unroll
    for (int u = 0; u < 4; ++u) {
        #pragma unroll
        for (int r = 0; r < 4; ++r) {
            int o = o_base + 16 * u + 4 * lhi + r;
            float so = S[o];
            #pragma unroll
            for (int s2 = 0; s2 < 4; ++s2) {
                float v = acc[u][s2][r] + so * lnbv[s2];
                v = v > 0.0f ? v : 0.0f;
                ob[((size_t)o << 16) + p0 + 16 * s2 + llo] = v;
            }
        }
    }
}

extern "C" void kernel_launch(void* const* d_in, const int* in_sizes, int n_in,
                              void* d_out, int out_size, void* d_ws, size_t ws_size,
                              hipStream_t stream) {
    const float* x   = (const float*)d_in[0];
    const float* y   = (const float*)d_in[1];
    const float* lnw = (const float*)d_in[2];
    const float* lnb = (const float*)d_in[3];
    const float* cw  = (const float*)d_in[4];
    float* out = (float*)d_out;

    // ws layout: cwb bf16 128 KiB | S 1 KiB
    unsigned short* cwb = (unsigned short*)d_ws;
    float* S            = (float*)((char*)d_ws + 131072);

    prep_kernel<<<256, 256, 0, stream>>>(cw, cwb, S);
    fused_kernel<<<1024, 1024, 0, stream>>>(x, y, lnw, lnb, cwb, S, out);
}